// Round 1
// baseline (719.774 us; speedup 1.0000x reference)
//
#include <hip/hip_runtime.h>
#include <math.h>

#define PI2 6.28318530717958647692f
#define BM 64
#define BN 64
#define BK 16

// ---------------------------------------------------------------------------
// Basis generation: B1T is the (scaled) DFT basis for the x-transform,
// laid out row-major (2048 rows = output spectral channels, 4096 cols = j).
// Row c<1024:  m=c:  (m==0 ? 1/4096 : 2*cos(2*pi*m*j/4096)/4096)
// Row c>=1024: m=c-1024: -2*sin(2*pi*m*j/4096)/4096   (row m=0 is all zeros)
// ---------------------------------------------------------------------------
__global__ __launch_bounds__(256) void gen_b1_kernel(float* __restrict__ B1T) {
    unsigned idx = blockIdx.x * 256u + threadIdx.x;   // 2048*4096 total
    int j = idx & 4095;
    int c = idx >> 12;
    const float inv_n = 1.0f / 4096.0f;
    float val;
    if (c < 1024) {
        int m = c;
        if (m == 0) {
            val = inv_n;
        } else {
            int t = (m * j) & 4095;                   // exact angle reduction
            val = 2.0f * inv_n * cosf((float)t * (PI2 / 4096.0f));
        }
    } else {
        int m = c - 1024;
        int t = (m * j) & 4095;
        val = -2.0f * inv_n * sinf((float)t * (PI2 / 4096.0f));
    }
    B1T[idx] = val;
}

// B2T: DFT basis for the T1 transform with S folded in.
// Row-major 1024 rows x 2048 cols (col k is the t-index; S[k] multiplies).
__global__ __launch_bounds__(256) void gen_b2_kernel(float* __restrict__ B2T,
                                                     const float* __restrict__ S) {
    unsigned idx = blockIdx.x * 256u + threadIdx.x;   // 1024*2048 total
    int k = idx & 2047;
    int p = idx >> 11;
    const float inv_n = 1.0f / 2048.0f;
    float val;
    if (p < 512) {
        if (p == 0) {
            val = inv_n;
        } else {
            int t = (p * k) & 2047;
            val = 2.0f * inv_n * cosf((float)t * (PI2 / 2048.0f));
        }
    } else {
        int q = p - 512;
        int t = (q * k) & 2047;
        val = -2.0f * inv_n * sinf((float)t * (PI2 / 2048.0f));
    }
    B2T[idx] = val * S[k];
}

// ---------------------------------------------------------------------------
// Generic fp32 NT-GEMM with split-K over two B pointers:
//   C[m,n] = sum_{k<H} A[m,k]*Blo[n*ldb+k] + sum_{k<H} A[m,H+k]*Bhi[n*ldb+k]
//            (+ bias[n] if bias != nullptr)
// All dims are multiples of the tile sizes (M=1024, N in {1024,2048,4096},
// H in {512,1024,2048}); no bounds checks needed.
// 64x64 tile, BK=16, 256 threads, 4x4 accumulators per thread.
// LDS tiles stored transposed [k][m] with +4 pad (stride 68 keeps float4
// alignment; staging-store aliasing is only 2-way, which is free on CDNA4).
// ---------------------------------------------------------------------------
__global__ __launch_bounds__(256) void gemm_nt_split(
    const float* __restrict__ A, int lda,
    const float* __restrict__ Blo,
    const float* __restrict__ Bhi, int ldb,
    float* __restrict__ C, int ldc,
    const float* __restrict__ bias,
    int H)
{
    __shared__ float As[BK][BM + 4];
    __shared__ float Bs[BK][BN + 4];

    const int t  = threadIdx.x;
    const int tx = t & 15;
    const int ty = t >> 4;
    const int bm = blockIdx.y * BM;
    const int bn = blockIdx.x * BN;

    const int srow = t >> 2;          // 0..63 (tile row for staging)
    const int scol = (t & 3) << 2;    // 0,4,8,12 (k offset for staging)

    float acc[4][4] = {};

    for (int phase = 0; phase < 2; ++phase) {
        const float* Aptr = A + (size_t)phase * H + (size_t)(bm + srow) * lda + scol;
        const float* Bp   = phase ? Bhi : Blo;
        const float* Bptr = Bp + (size_t)(bn + srow) * ldb + scol;

        for (int k0 = 0; k0 < H; k0 += BK) {
            float4 av = *(const float4*)(Aptr + k0);
            float4 bv = *(const float4*)(Bptr + k0);
            __syncthreads();          // previous tile fully consumed
            As[scol + 0][srow] = av.x;
            As[scol + 1][srow] = av.y;
            As[scol + 2][srow] = av.z;
            As[scol + 3][srow] = av.w;
            Bs[scol + 0][srow] = bv.x;
            Bs[scol + 1][srow] = bv.y;
            Bs[scol + 2][srow] = bv.z;
            Bs[scol + 3][srow] = bv.w;
            __syncthreads();
            #pragma unroll
            for (int kk = 0; kk < BK; ++kk) {
                float4 a4 = *(const float4*)&As[kk][ty << 2];
                float4 b4 = *(const float4*)&Bs[kk][tx << 2];
                float a[4] = {a4.x, a4.y, a4.z, a4.w};
                float b[4] = {b4.x, b4.y, b4.z, b4.w};
                #pragma unroll
                for (int i = 0; i < 4; ++i)
                    #pragma unroll
                    for (int j = 0; j < 4; ++j)
                        acc[i][j] = fmaf(a[i], b[j], acc[i][j]);
            }
        }
    }

    float4 bv4 = make_float4(0.f, 0.f, 0.f, 0.f);
    if (bias) bv4 = *(const float4*)(bias + bn + (tx << 2));
    #pragma unroll
    for (int i = 0; i < 4; ++i) {
        float4 o;
        o.x = acc[i][0] + bv4.x;
        o.y = acc[i][1] + bv4.y;
        o.z = acc[i][2] + bv4.z;
        o.w = acc[i][3] + bv4.w;
        *(float4*)(C + (size_t)(bm + (ty << 2) + i) * ldc + bn + (tx << 2)) = o;
    }
}

extern "C" void kernel_launch(void* const* d_in, const int* in_sizes, int n_in,
                              void* d_out, int out_size, void* d_ws, size_t ws_size,
                              hipStream_t stream) {
    const float* x    = (const float*)d_in[0];   // 1024 x 4096
    const float* Ur   = (const float*)d_in[1];   // 4096 x 512
    const float* Ui   = (const float*)d_in[2];   // 4096 x 512
    const float* S    = (const float*)d_in[3];   // 2048
    const float* Vr   = (const float*)d_in[4];   // 2048 x 1024
    const float* Vi   = (const float*)d_in[5];   // 2048 x 1024
    const float* bias = (const float*)d_in[6];   // 4096
    float* out = (float*)d_out;                  // 1024 x 4096

    // Workspace layout (floats): ~60 MB total
    float* ws  = (float*)d_ws;
    float* B1T = ws;                                   // 2048*4096
    float* B2T = B1T + (size_t)2048 * 4096;            // 1024*2048
    float* Xp  = B2T + (size_t)1024 * 2048;            // 1024*2048
    float* T1  = Xp  + (size_t)1024 * 2048;            // 1024*2048
    float* Yp  = T1  + (size_t)1024 * 2048;            // 1024*1024

    gen_b1_kernel<<<dim3((2048u * 4096u) / 256u), dim3(256), 0, stream>>>(B1T);
    gen_b2_kernel<<<dim3((1024u * 2048u) / 256u), dim3(256), 0, stream>>>(B2T, S);

    // Stage 1: X' = x @ B1T^T           (M=1024, N=2048, K=4096)
    gemm_nt_split<<<dim3(2048 / BN, 1024 / BM), 256, 0, stream>>>(
        x, 4096, B1T, B1T + 2048, 4096, Xp, 2048, nullptr, 2048);

    // Stage 2: T1 = X' @ [Vr|Vi]^T      (M=1024, N=2048, K=2048)
    gemm_nt_split<<<dim3(2048 / BN, 1024 / BM), 256, 0, stream>>>(
        Xp, 2048, Vr, Vi, 1024, T1, 2048, nullptr, 1024);

    // Stage 3: Y' = T1 @ B2T^T (S folded) (M=1024, N=1024, K=2048)
    gemm_nt_split<<<dim3(1024 / BN, 1024 / BM), 256, 0, stream>>>(
        T1, 2048, B2T, B2T + 1024, 2048, Yp, 1024, nullptr, 1024);

    // Stage 4: out = Y' @ [Ur|Ui]^T + bias (M=1024, N=4096, K=1024)
    gemm_nt_split<<<dim3(4096 / BN, 1024 / BM), 256, 0, stream>>>(
        Yp, 1024, Ur, Ui, 512, out, 4096, bias, 512);
}

// Round 2
// 322.490 us; speedup vs baseline: 2.2319x; 2.2319x over previous
//
#include <hip/hip_runtime.h>
#include <math.h>
#include <stdint.h>

#define PI2 6.28318530717958647692f

typedef __bf16 bf16x8 __attribute__((ext_vector_type(8)));
typedef float f32x4 __attribute__((ext_vector_type(4)));

typedef __attribute__((address_space(1))) const void gvoid_t;
typedef __attribute__((address_space(3))) void lvoid_t;

__device__ __forceinline__ void g2l16(const void* g, void* l) {
    __builtin_amdgcn_global_load_lds(
        reinterpret_cast<gvoid_t*>(reinterpret_cast<uintptr_t>(g)),
        reinterpret_cast<lvoid_t*>(reinterpret_cast<uintptr_t>(l)),
        16, 0, 0);
}

__device__ __forceinline__ short f2bf(float f) {
    unsigned u = __float_as_uint(f);
    u += 0x7FFFu + ((u >> 16) & 1u);          // round-to-nearest-even
    return (short)(u >> 16);
}

// ---------------------------------------------------------------------------
// Aux kernels: convert/pack inputs to bf16, generate DFT bases in bf16.
// ---------------------------------------------------------------------------
__global__ __launch_bounds__(256) void cvt_bf(const float* __restrict__ in,
                                              short* __restrict__ out) {
    unsigned i = blockIdx.x * 256u + threadIdx.x;
    out[i] = f2bf(in[i]);
}

// Vcat[t][c] : c<1024 -> Vr[t][c], else Vi[t][c-1024]   (2048 x 2048)
__global__ __launch_bounds__(256) void pack_v(const float* __restrict__ Vr,
                                              const float* __restrict__ Vi,
                                              short* __restrict__ out) {
    unsigned i = blockIdx.x * 256u + threadIdx.x;
    int t = i >> 11, c = i & 2047;
    float v = (c < 1024) ? Vr[t * 1024 + c] : Vi[t * 1024 + (c - 1024)];
    out[i] = f2bf(v);
}

// Ucat[o][c] : c<512 -> Ur[o][c], else Ui[o][c-512]     (4096 x 1024)
__global__ __launch_bounds__(256) void pack_u(const float* __restrict__ Ur,
                                              const float* __restrict__ Ui,
                                              short* __restrict__ out) {
    unsigned i = blockIdx.x * 256u + threadIdx.x;
    int o = i >> 10, c = i & 1023;
    float v = (c < 512) ? Ur[o * 512 + c] : Ui[o * 512 + (c - 512)];
    out[i] = f2bf(v);
}

// B1[c][j], 2048 x 4096: rows c<1024 = cos(m=c), rows c>=1024 = -sin(m=c-1024)
__global__ __launch_bounds__(256) void gen_b1_bf(short* __restrict__ B1) {
    unsigned idx = blockIdx.x * 256u + threadIdx.x;
    int j = idx & 4095;
    int c = idx >> 12;
    const float inv_n = 1.0f / 4096.0f;
    float val;
    if (c < 1024) {
        int m = c;
        if (m == 0) val = inv_n;
        else {
            int t = (m * j) & 4095;
            val = 2.0f * inv_n * cosf((float)t * (PI2 / 4096.0f));
        }
    } else {
        int m = c - 1024;
        int t = (m * j) & 4095;
        val = -2.0f * inv_n * sinf((float)t * (PI2 / 4096.0f));
    }
    B1[idx] = f2bf(val);
}

// B2[p][k], 1024 x 2048, with S[k] folded in.
__global__ __launch_bounds__(256) void gen_b2_bf(short* __restrict__ B2,
                                                 const float* __restrict__ S) {
    unsigned idx = blockIdx.x * 256u + threadIdx.x;
    int k = idx & 2047;
    int p = idx >> 11;
    const float inv_n = 1.0f / 2048.0f;
    float val;
    if (p < 512) {
        if (p == 0) val = inv_n;
        else {
            int t = (p * k) & 2047;
            val = 2.0f * inv_n * cosf((float)t * (PI2 / 2048.0f));
        }
    } else {
        int q = p - 512;
        int t = (q * k) & 2047;
        val = -2.0f * inv_n * sinf((float)t * (PI2 / 2048.0f));
    }
    B2[idx] = f2bf(val * S[k]);
}

// ---------------------------------------------------------------------------
// bf16 MFMA NT-GEMM (m97 structure): C[M,N] = A[M,K] @ B[N,K]^T (+bias)
// 128x128 tile, 256 threads (4 waves, 2x2 of 64x64), BK=32,
// global_load_lds width-16 staging, mfma_f32_16x16x32_bf16.
// All dims multiples of 128/32; no bounds checks.
// ---------------------------------------------------------------------------
template <bool OUT_F32>
__global__ __launch_bounds__(256) void gemm_bt_bf16(
    const short* __restrict__ A, int lda,
    const short* __restrict__ B, int ldb,
    void* __restrict__ Cv, int ldc,
    const float* __restrict__ bias, int K)
{
    __shared__ __align__(16) short As[128 * 32];
    __shared__ __align__(16) short Bs[128 * 32];

    const int tid  = threadIdx.x;
    const int wave = tid >> 6;
    const int lane = tid & 63;
    const int bm   = blockIdx.y << 7;
    const int bn   = blockIdx.x << 7;
    const int wm   = (wave >> 1) << 6;   // wave row offset in tile
    const int wn   = (wave & 1) << 6;    // wave col offset in tile
    const int l16  = lane & 15;
    const int quad = lane >> 4;

    f32x4 acc[4][4];
    #pragma unroll
    for (int i = 0; i < 4; ++i)
        #pragma unroll
        for (int j = 0; j < 4; ++j)
            acc[i][j] = (f32x4){0.f, 0.f, 0.f, 0.f};

    // Staging: linear 16B chunk L = pass*256 + wave*64 + lane over a
    // 128x32 bf16 tile (64 B per row -> row = L>>2, k-offset = (L&3)*8).
    const int L0 = wave * 64 + lane;
    const int r0 = L0 >> 2, c0 = (L0 & 3) << 3;
    const int L1 = 256 + L0;
    const int r1 = L1 >> 2, c1 = (L1 & 3) << 3;

    const short* Ag0 = A + (size_t)(bm + r0) * lda + c0;
    const short* Ag1 = A + (size_t)(bm + r1) * lda + c1;
    const short* Bg0 = B + (size_t)(bn + r0) * ldb + c0;
    const short* Bg1 = B + (size_t)(bn + r1) * ldb + c1;
    short* Al0 = As + (wave * 64) * 8;          // wave-uniform LDS bases
    short* Al1 = As + (256 + wave * 64) * 8;
    short* Bl0 = Bs + (wave * 64) * 8;
    short* Bl1 = Bs + (256 + wave * 64) * 8;

    for (int k0 = 0; k0 < K; k0 += 32) {
        __syncthreads();                 // previous tile fully consumed
        g2l16(Ag0 + k0, Al0);
        g2l16(Ag1 + k0, Al1);
        g2l16(Bg0 + k0, Bl0);
        g2l16(Bg1 + k0, Bl1);
        __syncthreads();                 // vmcnt(0) drain before barrier

        bf16x8 a[4], b[4];
        #pragma unroll
        for (int mt = 0; mt < 4; ++mt)
            a[mt] = *(const bf16x8*)(As + (wm + mt * 16 + l16) * 32 + quad * 8);
        #pragma unroll
        for (int nt = 0; nt < 4; ++nt)
            b[nt] = *(const bf16x8*)(Bs + (wn + nt * 16 + l16) * 32 + quad * 8);
        #pragma unroll
        for (int mt = 0; mt < 4; ++mt)
            #pragma unroll
            for (int nt = 0; nt < 4; ++nt)
                acc[mt][nt] = __builtin_amdgcn_mfma_f32_16x16x32_bf16(
                    a[mt], b[nt], acc[mt][nt], 0, 0, 0);
    }

    // Epilogue: C/D layout col = lane&15, row = quad*4 + r
    if (OUT_F32) {
        float* C = (float*)Cv;
        #pragma unroll
        for (int nt = 0; nt < 4; ++nt) {
            int col = bn + wn + nt * 16 + l16;
            float bv = bias ? bias[col] : 0.f;
            #pragma unroll
            for (int mt = 0; mt < 4; ++mt) {
                int rowb = bm + wm + mt * 16 + quad * 4;
                #pragma unroll
                for (int r = 0; r < 4; ++r)
                    C[(size_t)(rowb + r) * ldc + col] = acc[mt][nt][r] + bv;
            }
        }
    } else {
        short* C = (short*)Cv;
        #pragma unroll
        for (int nt = 0; nt < 4; ++nt) {
            int col = bn + wn + nt * 16 + l16;
            #pragma unroll
            for (int mt = 0; mt < 4; ++mt) {
                int rowb = bm + wm + mt * 16 + quad * 4;
                #pragma unroll
                for (int r = 0; r < 4; ++r)
                    C[(size_t)(rowb + r) * ldc + col] = f2bf(acc[mt][nt][r]);
            }
        }
    }
}

extern "C" void kernel_launch(void* const* d_in, const int* in_sizes, int n_in,
                              void* d_out, int out_size, void* d_ws, size_t ws_size,
                              hipStream_t stream) {
    const float* x    = (const float*)d_in[0];   // 1024 x 4096
    const float* Ur   = (const float*)d_in[1];   // 4096 x 512
    const float* Ui   = (const float*)d_in[2];   // 4096 x 512
    const float* S    = (const float*)d_in[3];   // 2048
    const float* Vr   = (const float*)d_in[4];   // 2048 x 1024
    const float* Vi   = (const float*)d_in[5];   // 2048 x 1024
    const float* bias = (const float*)d_in[6];   // 4096
    float* out = (float*)d_out;                  // 1024 x 4096

    // Workspace (bf16 shorts), ~56.6 MB total
    short* ws   = (short*)d_ws;
    short* x_bf = ws;                                  // 1024*4096
    short* B1   = x_bf + (size_t)1024 * 4096;          // 2048*4096
    short* Vcat = B1   + (size_t)2048 * 4096;          // 2048*2048
    short* B2   = Vcat + (size_t)2048 * 2048;          // 1024*2048
    short* Ucat = B2   + (size_t)1024 * 2048;          // 4096*1024
    short* Xp   = Ucat + (size_t)4096 * 1024;          // 1024*2048
    short* T1   = Xp   + (size_t)1024 * 2048;          // 1024*2048
    short* Yp   = T1   + (size_t)1024 * 2048;          // 1024*1024

    cvt_bf   <<<dim3(4194304u / 256u), 256, 0, stream>>>(x, x_bf);
    gen_b1_bf<<<dim3(8388608u / 256u), 256, 0, stream>>>(B1);
    pack_v   <<<dim3(4194304u / 256u), 256, 0, stream>>>(Vr, Vi, Vcat);
    gen_b2_bf<<<dim3(2097152u / 256u), 256, 0, stream>>>(B2, S);
    pack_u   <<<dim3(4194304u / 256u), 256, 0, stream>>>(Ur, Ui, Ucat);

    // Stage 1: X' = x @ B1^T            (M=1024, N=2048, K=4096)
    gemm_bt_bf16<false><<<dim3(16, 8), 256, 0, stream>>>(
        x_bf, 4096, B1, 4096, Xp, 2048, nullptr, 4096);

    // Stage 2: T1 = X' @ Vcat^T         (M=1024, N=2048, K=2048)
    gemm_bt_bf16<false><<<dim3(16, 8), 256, 0, stream>>>(
        Xp, 2048, Vcat, 2048, T1, 2048, nullptr, 2048);

    // Stage 3: Y' = T1 @ B2^T           (M=1024, N=1024, K=2048)
    gemm_bt_bf16<false><<<dim3(8, 8), 256, 0, stream>>>(
        T1, 2048, B2, 2048, Yp, 1024, nullptr, 2048);

    // Stage 4: out = Y' @ Ucat^T + bias (M=1024, N=4096, K=1024)
    gemm_bt_bf16<true><<<dim3(32, 8), 256, 0, stream>>>(
        Yp, 1024, Ucat, 1024, out, 4096, bias, 1024);
}

// Round 3
// 245.124 us; speedup vs baseline: 2.9364x; 1.3156x over previous
//
#include <hip/hip_runtime.h>
#include <math.h>
#include <stdint.h>

#define PI2 6.28318530717958647692f

typedef __bf16 bf16x8 __attribute__((ext_vector_type(8)));
typedef float f32x4 __attribute__((ext_vector_type(4)));

typedef __attribute__((address_space(1))) const void gvoid_t;
typedef __attribute__((address_space(3))) void lvoid_t;

__device__ __forceinline__ void g2l16(const void* g, void* l) {
    __builtin_amdgcn_global_load_lds(
        reinterpret_cast<gvoid_t*>(reinterpret_cast<uintptr_t>(g)),
        reinterpret_cast<lvoid_t*>(reinterpret_cast<uintptr_t>(l)),
        16, 0, 0);
}

__device__ __forceinline__ short f2bf(float f) {
    unsigned u = __float_as_uint(f);
    u += 0x7FFFu + ((u >> 16) & 1u);          // round-to-nearest-even
    return (short)(u >> 16);
}

// ---------------------------------------------------------------------------
// Aux kernels
// ---------------------------------------------------------------------------
__global__ __launch_bounds__(256) void cvt_bf(const float* __restrict__ in,
                                              short* __restrict__ out) {
    unsigned i = blockIdx.x * 256u + threadIdx.x;
    out[i] = f2bf(in[i]);
}

__global__ __launch_bounds__(256) void pack_v(const float* __restrict__ Vr,
                                              const float* __restrict__ Vi,
                                              short* __restrict__ out) {
    unsigned i = blockIdx.x * 256u + threadIdx.x;
    int t = i >> 11, c = i & 2047;
    float v = (c < 1024) ? Vr[t * 1024 + c] : Vi[t * 1024 + (c - 1024)];
    out[i] = f2bf(v);
}

__global__ __launch_bounds__(256) void pack_u(const float* __restrict__ Ur,
                                              const float* __restrict__ Ui,
                                              short* __restrict__ out) {
    unsigned i = blockIdx.x * 256u + threadIdx.x;
    int o = i >> 10, c = i & 1023;
    float v = (c < 512) ? Ur[o * 512 + c] : Ui[o * 512 + (c - 512)];
    out[i] = f2bf(v);
}

__global__ __launch_bounds__(256) void gen_b1_bf(short* __restrict__ B1) {
    unsigned idx = blockIdx.x * 256u + threadIdx.x;
    int j = idx & 4095;
    int c = idx >> 12;
    const float inv_n = 1.0f / 4096.0f;
    float val;
    if (c < 1024) {
        int m = c;
        if (m == 0) val = inv_n;
        else {
            int t = (m * j) & 4095;
            val = 2.0f * inv_n * cosf((float)t * (PI2 / 4096.0f));
        }
    } else {
        int m = c - 1024;
        int t = (m * j) & 4095;
        val = -2.0f * inv_n * sinf((float)t * (PI2 / 4096.0f));
    }
    B1[idx] = f2bf(val);
}

__global__ __launch_bounds__(256) void gen_b2_bf(short* __restrict__ B2,
                                                 const float* __restrict__ S) {
    unsigned idx = blockIdx.x * 256u + threadIdx.x;
    int k = idx & 2047;
    int p = idx >> 11;
    const float inv_n = 1.0f / 2048.0f;
    float val;
    if (p < 512) {
        if (p == 0) val = inv_n;
        else {
            int t = (p * k) & 2047;
            val = 2.0f * inv_n * cosf((float)t * (PI2 / 2048.0f));
        }
    } else {
        int q = p - 512;
        int t = (q * k) & 2047;
        val = -2.0f * inv_n * sinf((float)t * (PI2 / 2048.0f));
    }
    B2[idx] = f2bf(val * S[k]);
}

// ---------------------------------------------------------------------------
// Split-K bf16 MFMA NT-GEMM: partial plane z gets A/B k-range
// [z*Kpart, (z+1)*Kpart); f32 partials at P + z*MN.
// 128x128 tile, 256 threads, BK=32, m97 structure.
// ---------------------------------------------------------------------------
__global__ __launch_bounds__(256) void gemm_bt_sk(
    const short* __restrict__ A, int lda,
    const short* __restrict__ B, int ldb,
    float* __restrict__ P, int ldc, size_t planeMN,
    int Kpart)
{
    __shared__ __align__(16) short As[128 * 32];
    __shared__ __align__(16) short Bs[128 * 32];

    const int tid  = threadIdx.x;
    const int wave = tid >> 6;
    const int lane = tid & 63;
    const int bm   = blockIdx.y << 7;
    const int bn   = blockIdx.x << 7;
    const int z    = blockIdx.z;
    const int wm   = (wave >> 1) << 6;
    const int wn   = (wave & 1) << 6;
    const int l16  = lane & 15;
    const int quad = lane >> 4;

    A += (size_t)z * Kpart;
    B += (size_t)z * Kpart;
    float* C = P + (size_t)z * planeMN;

    f32x4 acc[4][4];
    #pragma unroll
    for (int i = 0; i < 4; ++i)
        #pragma unroll
        for (int j = 0; j < 4; ++j)
            acc[i][j] = (f32x4){0.f, 0.f, 0.f, 0.f};

    const int L0 = wave * 64 + lane;
    const int r0 = L0 >> 2, c0 = (L0 & 3) << 3;
    const int L1 = 256 + L0;
    const int r1 = L1 >> 2, c1 = (L1 & 3) << 3;

    const short* Ag0 = A + (size_t)(bm + r0) * lda + c0;
    const short* Ag1 = A + (size_t)(bm + r1) * lda + c1;
    const short* Bg0 = B + (size_t)(bn + r0) * ldb + c0;
    const short* Bg1 = B + (size_t)(bn + r1) * ldb + c1;
    short* Al0 = As + (wave * 64) * 8;
    short* Al1 = As + (256 + wave * 64) * 8;
    short* Bl0 = Bs + (wave * 64) * 8;
    short* Bl1 = Bs + (256 + wave * 64) * 8;

    for (int k0 = 0; k0 < Kpart; k0 += 32) {
        __syncthreads();
        g2l16(Ag0 + k0, Al0);
        g2l16(Ag1 + k0, Al1);
        g2l16(Bg0 + k0, Bl0);
        g2l16(Bg1 + k0, Bl1);
        __syncthreads();

        bf16x8 a[4], b[4];
        #pragma unroll
        for (int mt = 0; mt < 4; ++mt)
            a[mt] = *(const bf16x8*)(As + (wm + mt * 16 + l16) * 32 + quad * 8);
        #pragma unroll
        for (int nt = 0; nt < 4; ++nt)
            b[nt] = *(const bf16x8*)(Bs + (wn + nt * 16 + l16) * 32 + quad * 8);
        #pragma unroll
        for (int mt = 0; mt < 4; ++mt)
            #pragma unroll
            for (int nt = 0; nt < 4; ++nt)
                acc[mt][nt] = __builtin_amdgcn_mfma_f32_16x16x32_bf16(
                    a[mt], b[nt], acc[mt][nt], 0, 0, 0);
    }

    #pragma unroll
    for (int nt = 0; nt < 4; ++nt) {
        int col = bn + wn + nt * 16 + l16;
        #pragma unroll
        for (int mt = 0; mt < 4; ++mt) {
            int rowb = bm + wm + mt * 16 + quad * 4;
            #pragma unroll
            for (int r = 0; r < 4; ++r)
                C[(size_t)(rowb + r) * ldc + col] = acc[mt][nt][r];
        }
    }
}

// Reduce SK f32 partial planes -> bf16
__global__ __launch_bounds__(256) void reduce_to_bf(const float* __restrict__ P,
                                                    size_t quarterMN, int SK,
                                                    uint2* __restrict__ out) {
    size_t i = blockIdx.x * 256u + threadIdx.x;
    const float4* P4 = (const float4*)P;
    float4 s = P4[i];
    for (int z = 1; z < SK; ++z) {
        float4 v = P4[(size_t)z * quarterMN + i];
        s.x += v.x; s.y += v.y; s.z += v.z; s.w += v.w;
    }
    uint2 o;
    o.x = (unsigned)(unsigned short)f2bf(s.x) | ((unsigned)(unsigned short)f2bf(s.y) << 16);
    o.y = (unsigned)(unsigned short)f2bf(s.z) | ((unsigned)(unsigned short)f2bf(s.w) << 16);
    out[i] = o;
}

// Reduce SK f32 partial planes + bias -> f32 (ldc = 4096)
__global__ __launch_bounds__(256) void reduce_to_f32_bias(const float* __restrict__ P,
                                                          size_t quarterMN, int SK,
                                                          const float* __restrict__ bias,
                                                          float4* __restrict__ out) {
    size_t i = blockIdx.x * 256u + threadIdx.x;
    const float4* P4 = (const float4*)P;
    float4 s = P4[i];
    for (int z = 1; z < SK; ++z) {
        float4 v = P4[(size_t)z * quarterMN + i];
        s.x += v.x; s.y += v.y; s.z += v.z; s.w += v.w;
    }
    float4 b = ((const float4*)bias)[i & 1023];   // ldc 4096 -> 1024 float4 groups
    s.x += b.x; s.y += b.y; s.z += b.z; s.w += b.w;
    out[i] = s;
}

// ---------------------------------------------------------------------------
// Fallback direct GEMM (round-2 path) if ws is too small for partials
// ---------------------------------------------------------------------------
template <bool OUT_F32>
__global__ __launch_bounds__(256) void gemm_bt_bf16(
    const short* __restrict__ A, int lda,
    const short* __restrict__ B, int ldb,
    void* __restrict__ Cv, int ldc,
    const float* __restrict__ bias, int K)
{
    __shared__ __align__(16) short As[128 * 32];
    __shared__ __align__(16) short Bs[128 * 32];

    const int tid  = threadIdx.x;
    const int wave = tid >> 6;
    const int lane = tid & 63;
    const int bm   = blockIdx.y << 7;
    const int bn   = blockIdx.x << 7;
    const int wm   = (wave >> 1) << 6;
    const int wn   = (wave & 1) << 6;
    const int l16  = lane & 15;
    const int quad = lane >> 4;

    f32x4 acc[4][4];
    #pragma unroll
    for (int i = 0; i < 4; ++i)
        #pragma unroll
        for (int j = 0; j < 4; ++j)
            acc[i][j] = (f32x4){0.f, 0.f, 0.f, 0.f};

    const int L0 = wave * 64 + lane;
    const int r0 = L0 >> 2, c0 = (L0 & 3) << 3;
    const int L1 = 256 + L0;
    const int r1 = L1 >> 2, c1 = (L1 & 3) << 3;

    const short* Ag0 = A + (size_t)(bm + r0) * lda + c0;
    const short* Ag1 = A + (size_t)(bm + r1) * lda + c1;
    const short* Bg0 = B + (size_t)(bn + r0) * ldb + c0;
    const short* Bg1 = B + (size_t)(bn + r1) * ldb + c1;
    short* Al0 = As + (wave * 64) * 8;
    short* Al1 = As + (256 + wave * 64) * 8;
    short* Bl0 = Bs + (wave * 64) * 8;
    short* Bl1 = Bs + (256 + wave * 64) * 8;

    for (int k0 = 0; k0 < K; k0 += 32) {
        __syncthreads();
        g2l16(Ag0 + k0, Al0);
        g2l16(Ag1 + k0, Al1);
        g2l16(Bg0 + k0, Bl0);
        g2l16(Bg1 + k0, Bl1);
        __syncthreads();

        bf16x8 a[4], b[4];
        #pragma unroll
        for (int mt = 0; mt < 4; ++mt)
            a[mt] = *(const bf16x8*)(As + (wm + mt * 16 + l16) * 32 + quad * 8);
        #pragma unroll
        for (int nt = 0; nt < 4; ++nt)
            b[nt] = *(const bf16x8*)(Bs + (wn + nt * 16 + l16) * 32 + quad * 8);
        #pragma unroll
        for (int mt = 0; mt < 4; ++mt)
            #pragma unroll
            for (int nt = 0; nt < 4; ++nt)
                acc[mt][nt] = __builtin_amdgcn_mfma_f32_16x16x32_bf16(
                    a[mt], b[nt], acc[mt][nt], 0, 0, 0);
    }

    if (OUT_F32) {
        float* C = (float*)Cv;
        #pragma unroll
        for (int nt = 0; nt < 4; ++nt) {
            int col = bn + wn + nt * 16 + l16;
            float bv = bias ? bias[col] : 0.f;
            #pragma unroll
            for (int mt = 0; mt < 4; ++mt) {
                int rowb = bm + wm + mt * 16 + quad * 4;
                #pragma unroll
                for (int r = 0; r < 4; ++r)
                    C[(size_t)(rowb + r) * ldc + col] = acc[mt][nt][r] + bv;
            }
        }
    } else {
        short* C = (short*)Cv;
        #pragma unroll
        for (int nt = 0; nt < 4; ++nt) {
            int col = bn + wn + nt * 16 + l16;
            #pragma unroll
            for (int mt = 0; mt < 4; ++mt) {
                int rowb = bm + wm + mt * 16 + quad * 4;
                #pragma unroll
                for (int r = 0; r < 4; ++r)
                    C[(size_t)(rowb + r) * ldc + col] = f2bf(acc[mt][nt][r]);
            }
        }
    }
}

extern "C" void kernel_launch(void* const* d_in, const int* in_sizes, int n_in,
                              void* d_out, int out_size, void* d_ws, size_t ws_size,
                              hipStream_t stream) {
    const float* x    = (const float*)d_in[0];
    const float* Ur   = (const float*)d_in[1];
    const float* Ui   = (const float*)d_in[2];
    const float* S    = (const float*)d_in[3];
    const float* Vr   = (const float*)d_in[4];
    const float* Vi   = (const float*)d_in[5];
    const float* bias = (const float*)d_in[6];
    float* out = (float*)d_out;

    short* ws   = (short*)d_ws;
    short* x_bf = ws;                                  // 1024*4096
    short* B1   = x_bf + (size_t)1024 * 4096;          // 2048*4096
    short* Vcat = B1   + (size_t)2048 * 4096;          // 2048*2048
    short* B2   = Vcat + (size_t)2048 * 2048;          // 1024*2048
    short* Ucat = B2   + (size_t)1024 * 2048;          // 4096*1024
    short* Xp   = Ucat + (size_t)4096 * 1024;          // 1024*2048
    short* T1   = Xp   + (size_t)1024 * 2048;          // 1024*2048
    short* Yp   = T1   + (size_t)1024 * 2048;          // 1024*1024
    float* Pp   = (float*)(Yp + (size_t)1024 * 1024);  // partials: up to 8.388M f32

    const size_t need = ((size_t)(Yp + (size_t)1024 * 1024) - (size_t)d_ws)
                        + (size_t)8 * 1024 * 1024 * 4 /*33.5MB partials*/;

    cvt_bf   <<<dim3(4194304u / 256u), 256, 0, stream>>>(x, x_bf);
    gen_b1_bf<<<dim3(8388608u / 256u), 256, 0, stream>>>(B1);
    pack_v   <<<dim3(4194304u / 256u), 256, 0, stream>>>(Vr, Vi, Vcat);
    gen_b2_bf<<<dim3(2097152u / 256u), 256, 0, stream>>>(B2, S);
    pack_u   <<<dim3(4194304u / 256u), 256, 0, stream>>>(Ur, Ui, Ucat);

    if (ws_size >= need) {
        // Stage 1: X' = x @ B1^T   (1024x2048, K=4096, SK=4 -> 512 blocks)
        gemm_bt_sk<<<dim3(16, 8, 4), 256, 0, stream>>>(
            x_bf, 4096, B1, 4096, Pp, 2048, (size_t)1024 * 2048, 1024);
        reduce_to_bf<<<dim3(2048), 256, 0, stream>>>(
            Pp, (size_t)1024 * 2048 / 4, 4, (uint2*)Xp);

        // Stage 2: T1 = X' @ Vcat^T (1024x2048, K=2048, SK=4 -> 512 blocks)
        gemm_bt_sk<<<dim3(16, 8, 4), 256, 0, stream>>>(
            Xp, 2048, Vcat, 2048, Pp, 2048, (size_t)1024 * 2048, 512);
        reduce_to_bf<<<dim3(2048), 256, 0, stream>>>(
            Pp, (size_t)1024 * 2048 / 4, 4, (uint2*)T1);

        // Stage 3: Y' = T1 @ B2^T  (1024x1024, K=2048, SK=8 -> 512 blocks)
        gemm_bt_sk<<<dim3(8, 8, 8), 256, 0, stream>>>(
            T1, 2048, B2, 2048, Pp, 1024, (size_t)1024 * 1024, 256);
        reduce_to_bf<<<dim3(1024), 256, 0, stream>>>(
            Pp, (size_t)1024 * 1024 / 4, 8, (uint2*)Yp);

        // Stage 4: out = Y' @ Ucat^T + bias (1024x4096, K=1024, SK=2 -> 512)
        gemm_bt_sk<<<dim3(32, 8, 2), 256, 0, stream>>>(
            Yp, 1024, Ucat, 1024, Pp, 4096, (size_t)1024 * 4096, 512);
        reduce_to_f32_bias<<<dim3(4096), 256, 0, stream>>>(
            Pp, (size_t)1024 * 4096 / 4, 2, bias, (float4*)out);
    } else {
        gemm_bt_bf16<false><<<dim3(16, 8), 256, 0, stream>>>(
            x_bf, 4096, B1, 4096, Xp, 2048, nullptr, 4096);
        gemm_bt_bf16<false><<<dim3(16, 8), 256, 0, stream>>>(
            Xp, 2048, Vcat, 2048, T1, 2048, nullptr, 2048);
        gemm_bt_bf16<false><<<dim3(8, 8), 256, 0, stream>>>(
            T1, 2048, B2, 2048, Yp, 1024, nullptr, 2048);
        gemm_bt_bf16<true><<<dim3(32, 8), 256, 0, stream>>>(
            Yp, 1024, Ucat, 1024, out, 4096, bias, 1024);
    }
}

// Round 4
// 215.031 us; speedup vs baseline: 3.3473x; 1.1399x over previous
//
#include <hip/hip_runtime.h>
#include <math.h>
#include <stdint.h>

#define PI2 6.28318530717958647692f

typedef __bf16 bf16x8 __attribute__((ext_vector_type(8)));
typedef float f32x4 __attribute__((ext_vector_type(4)));

typedef __attribute__((address_space(1))) const void gvoid_t;
typedef __attribute__((address_space(3))) void lvoid_t;

__device__ __forceinline__ void g2l16(const void* g, void* l) {
    __builtin_amdgcn_global_load_lds(
        reinterpret_cast<gvoid_t*>(reinterpret_cast<uintptr_t>(g)),
        reinterpret_cast<lvoid_t*>(reinterpret_cast<uintptr_t>(l)),
        16, 0, 0);
}

__device__ __forceinline__ short f2bf(float f) {
    unsigned u = __float_as_uint(f);
    u += 0x7FFFu + ((u >> 16) & 1u);          // round-to-nearest-even
    return (short)(u >> 16);
}

__device__ __forceinline__ unsigned pack2bf(float a, float b) {
    return (unsigned)(unsigned short)f2bf(a) |
           ((unsigned)(unsigned short)f2bf(b) << 16);
}

// ---------------------------------------------------------------------------
// Fused aux kernel: one launch generates/converts all five bf16 operand
// arrays. Region boundaries are multiples of 256 -> no intra-wave divergence.
//   [0,        4194304): x_bf  = bf16(x)                    1024x4096
//   [4194304, 12582912): B1    = DFT basis n=4096           2048x4096
//   [12582912,16777216): Vcat  = [Vr|Vi]                    2048x2048
//   [16777216,18874368): B2    = DFT basis n=2048 * S[k]    1024x2048
//   [18874368,23068672): Ucat  = [Ur|Ui]                    4096x1024
// ---------------------------------------------------------------------------
__global__ __launch_bounds__(256) void aux_all(
    const float* __restrict__ x,
    const float* __restrict__ Ur, const float* __restrict__ Ui,
    const float* __restrict__ S,
    const float* __restrict__ Vr, const float* __restrict__ Vi,
    short* __restrict__ x_bf, short* __restrict__ B1,
    short* __restrict__ Vcat, short* __restrict__ B2,
    short* __restrict__ Ucat)
{
    unsigned idx = blockIdx.x * 256u + threadIdx.x;
    if (idx < 4194304u) {
        x_bf[idx] = f2bf(x[idx]);
    } else if (idx < 12582912u) {
        unsigned i = idx - 4194304u;
        int j = i & 4095, c = i >> 12;
        const float inv_n = 1.0f / 4096.0f;
        float val;
        if (c < 1024) {
            if (c == 0) val = inv_n;
            else {
                int t = (c * j) & 4095;
                val = 2.0f * inv_n * cosf((float)t * (PI2 / 4096.0f));
            }
        } else {
            int m = c - 1024;
            int t = (m * j) & 4095;
            val = -2.0f * inv_n * sinf((float)t * (PI2 / 4096.0f));
        }
        B1[i] = f2bf(val);
    } else if (idx < 16777216u) {
        unsigned i = idx - 12582912u;
        int t = i >> 11, c = i & 2047;
        float v = (c < 1024) ? Vr[t * 1024 + c] : Vi[t * 1024 + (c - 1024)];
        Vcat[i] = f2bf(v);
    } else if (idx < 18874368u) {
        unsigned i = idx - 16777216u;
        int k = i & 2047, p = i >> 11;
        const float inv_n = 1.0f / 2048.0f;
        float val;
        if (p < 512) {
            if (p == 0) val = inv_n;
            else {
                int t = (p * k) & 2047;
                val = 2.0f * inv_n * cosf((float)t * (PI2 / 2048.0f));
            }
        } else {
            int q = p - 512;
            int t = (q * k) & 2047;
            val = -2.0f * inv_n * sinf((float)t * (PI2 / 2048.0f));
        }
        B2[i] = f2bf(val * S[k]);
    } else {
        unsigned i = idx - 18874368u;
        int o = i >> 10, c = i & 1023;
        float v = (c < 512) ? Ur[o * 512 + c] : Ui[o * 512 + (c - 512)];
        Ucat[i] = f2bf(v);
    }
}

// ---------------------------------------------------------------------------
// Split-K bf16 MFMA NT-GEMM, BK=64, bf16 partial output planes.
// 128x128 tile, 256 threads (2x2 waves of 64x64), 32 KB LDS,
// __launch_bounds__(256,4) -> 4 blocks/CU, VGPR capped at 128.
// LDS layout: row-major 128x64 bf16 (128 B/row = 8 16B-chunks). Chunk c of
// row r holds GLOBAL chunk (c ^ (r&7)) — XOR swizzle applied on the global
// source address (global_load_lds dst must stay linear). Fragment reads then
// use chunk (cg ^ (r&7)): the quad's 16 lanes spread over 8 bank-quads ->
// 2-way aliasing only (free).
// ---------------------------------------------------------------------------
__global__ __launch_bounds__(256, 4) void gemm_bt_sk64(
    const short* __restrict__ A, int lda,
    const short* __restrict__ B, int ldb,
    short* __restrict__ P, int ldc, size_t planeMN,
    int Kpart)
{
    __shared__ __align__(16) short As[128 * 64];
    __shared__ __align__(16) short Bs[128 * 64];

    const int tid  = threadIdx.x;
    const int wave = tid >> 6;
    const int lane = tid & 63;
    const int bm   = blockIdx.y << 7;
    const int bn   = blockIdx.x << 7;
    const int wm   = (wave >> 1) << 6;
    const int wn   = (wave & 1) << 6;
    const int l16  = lane & 15;
    const int quad = lane >> 4;
    const int rk   = l16 & 7;          // row&7 for all fragment rows

    A += (size_t)blockIdx.z * Kpart;
    B += (size_t)blockIdx.z * Kpart;
    short* C = P + (size_t)blockIdx.z * planeMN;

    f32x4 acc[4][4];
    #pragma unroll
    for (int i = 0; i < 4; ++i)
        #pragma unroll
        for (int j = 0; j < 4; ++j)
            acc[i][j] = (f32x4){0.f, 0.f, 0.f, 0.f};

    // Staging: 4 chunks per thread per matrix; LDS slot L = p*256+wave*64+lane,
    // row = L>>3, lds chunk c8 = L&7, global chunk = c8 ^ (row&7).
    int aoff[4], boff[4], loff[4];
    #pragma unroll
    for (int p = 0; p < 4; ++p) {
        int L   = p * 256 + wave * 64 + lane;
        int row = L >> 3;
        int swz = (L & 7) ^ (row & 7);
        aoff[p] = (bm + row) * lda + swz * 8;
        boff[p] = (bn + row) * ldb + swz * 8;
        loff[p] = L * 8;
    }

    for (int k0 = 0; k0 < Kpart; k0 += 64) {
        __syncthreads();
        #pragma unroll
        for (int p = 0; p < 4; ++p) g2l16(A + aoff[p] + k0, As + loff[p]);
        #pragma unroll
        for (int p = 0; p < 4; ++p) g2l16(B + boff[p] + k0, Bs + loff[p]);
        __syncthreads();

        #pragma unroll
        for (int h = 0; h < 2; ++h) {
            const int cs8 = ((((h << 2) | quad) ^ rk) << 3);  // short offset
            bf16x8 b[4];
            #pragma unroll
            for (int nt = 0; nt < 4; ++nt)
                b[nt] = *(const bf16x8*)(Bs + (wn + nt * 16 + l16) * 64 + cs8);
            #pragma unroll
            for (int mt = 0; mt < 4; ++mt) {
                bf16x8 a = *(const bf16x8*)(As + (wm + mt * 16 + l16) * 64 + cs8);
                #pragma unroll
                for (int nt = 0; nt < 4; ++nt)
                    acc[mt][nt] = __builtin_amdgcn_mfma_f32_16x16x32_bf16(
                        a, b[nt], acc[mt][nt], 0, 0, 0);
            }
        }
    }

    // Epilogue: bf16 partial plane. C/D layout col=lane&15, row=quad*4+r.
    #pragma unroll
    for (int nt = 0; nt < 4; ++nt) {
        int col = bn + wn + nt * 16 + l16;
        #pragma unroll
        for (int mt = 0; mt < 4; ++mt) {
            int rowb = bm + wm + mt * 16 + quad * 4;
            #pragma unroll
            for (int r = 0; r < 4; ++r)
                C[(size_t)(rowb + r) * ldc + col] = f2bf(acc[mt][nt][r]);
        }
    }
}

// ---------------------------------------------------------------------------
// Reduce SK bf16 partial planes -> bf16 (8 elems/thread, 16B vector I/O)
// ---------------------------------------------------------------------------
__global__ __launch_bounds__(256) void reduce_bf(const short* __restrict__ P,
                                                 size_t MN, int SK,
                                                 short* __restrict__ out) {
    size_t i = blockIdx.x * 256u + threadIdx.x;     // < MN/8
    const uint4* P4 = (const uint4*)P;
    size_t stride = MN >> 3;
    float s[8] = {0,0,0,0,0,0,0,0};
    for (int z = 0; z < SK; ++z) {
        uint4 v = P4[(size_t)z * stride + i];
        s[0] += __uint_as_float(v.x << 16);
        s[1] += __uint_as_float(v.x & 0xFFFF0000u);
        s[2] += __uint_as_float(v.y << 16);
        s[3] += __uint_as_float(v.y & 0xFFFF0000u);
        s[4] += __uint_as_float(v.z << 16);
        s[5] += __uint_as_float(v.z & 0xFFFF0000u);
        s[6] += __uint_as_float(v.w << 16);
        s[7] += __uint_as_float(v.w & 0xFFFF0000u);
    }
    uint4 o;
    o.x = pack2bf(s[0], s[1]);
    o.y = pack2bf(s[2], s[3]);
    o.z = pack2bf(s[4], s[5]);
    o.w = pack2bf(s[6], s[7]);
    ((uint4*)out)[i] = o;
}

// Reduce SK bf16 partial planes + bias -> f32 (ldc = 4096)
__global__ __launch_bounds__(256) void reduce_f32_bias(const short* __restrict__ P,
                                                       size_t MN, int SK,
                                                       const float* __restrict__ bias,
                                                       float* __restrict__ out) {
    size_t i = blockIdx.x * 256u + threadIdx.x;     // < MN/8
    const uint4* P4 = (const uint4*)P;
    size_t stride = MN >> 3;
    float s[8] = {0,0,0,0,0,0,0,0};
    for (int z = 0; z < SK; ++z) {
        uint4 v = P4[(size_t)z * stride + i];
        s[0] += __uint_as_float(v.x << 16);
        s[1] += __uint_as_float(v.x & 0xFFFF0000u);
        s[2] += __uint_as_float(v.y << 16);
        s[3] += __uint_as_float(v.y & 0xFFFF0000u);
        s[4] += __uint_as_float(v.z << 16);
        s[5] += __uint_as_float(v.z & 0xFFFF0000u);
        s[6] += __uint_as_float(v.w << 16);
        s[7] += __uint_as_float(v.w & 0xFFFF0000u);
    }
    const float4* b4 = (const float4*)(bias + ((i & 511) << 3));
    float4 b0 = b4[0], b1 = b4[1];
    float4 o0 = {s[0] + b0.x, s[1] + b0.y, s[2] + b0.z, s[3] + b0.w};
    float4 o1 = {s[4] + b1.x, s[5] + b1.y, s[6] + b1.z, s[7] + b1.w};
    ((float4*)out)[i * 2]     = o0;
    ((float4*)out)[i * 2 + 1] = o1;
}

// ---------------------------------------------------------------------------
// Fallback direct GEMM (round-2 proven path) if ws is too small for partials
// ---------------------------------------------------------------------------
template <bool OUT_F32>
__global__ __launch_bounds__(256) void gemm_bt_bf16(
    const short* __restrict__ A, int lda,
    const short* __restrict__ B, int ldb,
    void* __restrict__ Cv, int ldc,
    const float* __restrict__ bias, int K)
{
    __shared__ __align__(16) short As[128 * 32];
    __shared__ __align__(16) short Bs[128 * 32];

    const int tid  = threadIdx.x;
    const int wave = tid >> 6;
    const int lane = tid & 63;
    const int bm   = blockIdx.y << 7;
    const int bn   = blockIdx.x << 7;
    const int wm   = (wave >> 1) << 6;
    const int wn   = (wave & 1) << 6;
    const int l16  = lane & 15;
    const int quad = lane >> 4;

    f32x4 acc[4][4];
    #pragma unroll
    for (int i = 0; i < 4; ++i)
        #pragma unroll
        for (int j = 0; j < 4; ++j)
            acc[i][j] = (f32x4){0.f, 0.f, 0.f, 0.f};

    const int L0 = wave * 64 + lane;
    const int r0 = L0 >> 2, c0 = (L0 & 3) << 3;
    const int L1 = 256 + L0;
    const int r1 = L1 >> 2, c1 = (L1 & 3) << 3;

    const short* Ag0 = A + (size_t)(bm + r0) * lda + c0;
    const short* Ag1 = A + (size_t)(bm + r1) * lda + c1;
    const short* Bg0 = B + (size_t)(bn + r0) * ldb + c0;
    const short* Bg1 = B + (size_t)(bn + r1) * ldb + c1;
    short* Al0 = As + (wave * 64) * 8;
    short* Al1 = As + (256 + wave * 64) * 8;
    short* Bl0 = Bs + (wave * 64) * 8;
    short* Bl1 = Bs + (256 + wave * 64) * 8;

    for (int k0 = 0; k0 < K; k0 += 32) {
        __syncthreads();
        g2l16(Ag0 + k0, Al0);
        g2l16(Ag1 + k0, Al1);
        g2l16(Bg0 + k0, Bl0);
        g2l16(Bg1 + k0, Bl1);
        __syncthreads();

        bf16x8 a[4], b[4];
        #pragma unroll
        for (int mt = 0; mt < 4; ++mt)
            a[mt] = *(const bf16x8*)(As + (wm + mt * 16 + l16) * 32 + quad * 8);
        #pragma unroll
        for (int nt = 0; nt < 4; ++nt)
            b[nt] = *(const bf16x8*)(Bs + (wn + nt * 16 + l16) * 32 + quad * 8);
        #pragma unroll
        for (int mt = 0; mt < 4; ++mt)
            #pragma unroll
            for (int nt = 0; nt < 4; ++nt)
                acc[mt][nt] = __builtin_amdgcn_mfma_f32_16x16x32_bf16(
                    a[mt], b[nt], acc[mt][nt], 0, 0, 0);
    }

    if (OUT_F32) {
        float* C = (float*)Cv;
        #pragma unroll
        for (int nt = 0; nt < 4; ++nt) {
            int col = bn + wn + nt * 16 + l16;
            float bv = bias ? bias[col] : 0.f;
            #pragma unroll
            for (int mt = 0; mt < 4; ++mt) {
                int rowb = bm + wm + mt * 16 + quad * 4;
                #pragma unroll
                for (int r = 0; r < 4; ++r)
                    C[(size_t)(rowb + r) * ldc + col] = acc[mt][nt][r] + bv;
            }
        }
    } else {
        short* C = (short*)Cv;
        #pragma unroll
        for (int nt = 0; nt < 4; ++nt) {
            int col = bn + wn + nt * 16 + l16;
            #pragma unroll
            for (int mt = 0; mt < 4; ++mt) {
                int rowb = bm + wm + mt * 16 + quad * 4;
                #pragma unroll
                for (int r = 0; r < 4; ++r)
                    C[(size_t)(rowb + r) * ldc + col] = f2bf(acc[mt][nt][r]);
            }
        }
    }
}

extern "C" void kernel_launch(void* const* d_in, const int* in_sizes, int n_in,
                              void* d_out, int out_size, void* d_ws, size_t ws_size,
                              hipStream_t stream) {
    const float* x    = (const float*)d_in[0];
    const float* Ur   = (const float*)d_in[1];
    const float* Ui   = (const float*)d_in[2];
    const float* S    = (const float*)d_in[3];
    const float* Vr   = (const float*)d_in[4];
    const float* Vi   = (const float*)d_in[5];
    const float* bias = (const float*)d_in[6];
    float* out = (float*)d_out;

    short* ws   = (short*)d_ws;
    short* x_bf = ws;                                  // 1024*4096
    short* B1   = x_bf + (size_t)1024 * 4096;          // 2048*4096
    short* Vcat = B1   + (size_t)2048 * 4096;          // 2048*2048
    short* B2   = Vcat + (size_t)2048 * 2048;          // 1024*2048
    short* Ucat = B2   + (size_t)1024 * 2048;          // 4096*1024
    short* Xp   = Ucat + (size_t)4096 * 1024;          // 1024*2048
    short* T1   = Xp   + (size_t)1024 * 2048;          // 1024*2048
    short* Yp   = T1   + (size_t)1024 * 2048;          // 1024*1024
    short* Pp   = Yp   + (size_t)1024 * 1024;          // partials: 16.78M shorts

    const size_t need = ((size_t)(Pp + (size_t)8 * 1024 * 2048) - (size_t)d_ws);

    aux_all<<<dim3(23068672u / 256u), 256, 0, stream>>>(
        x, Ur, Ui, S, Vr, Vi, x_bf, B1, Vcat, B2, Ucat);

    if (ws_size >= need) {
        // Stage 1: X' = x @ B1^T   (1024x2048, K=4096, SK=8 -> 1024 blocks)
        gemm_bt_sk64<<<dim3(16, 8, 8), 256, 0, stream>>>(
            x_bf, 4096, B1, 4096, Pp, 2048, (size_t)1024 * 2048, 512);
        reduce_bf<<<dim3(1024), 256, 0, stream>>>(
            Pp, (size_t)1024 * 2048, 8, Xp);

        // Stage 2: T1 = X' @ Vcat^T (1024x2048, K=2048, SK=8 -> 1024 blocks)
        gemm_bt_sk64<<<dim3(16, 8, 8), 256, 0, stream>>>(
            Xp, 2048, Vcat, 2048, Pp, 2048, (size_t)1024 * 2048, 256);
        reduce_bf<<<dim3(1024), 256, 0, stream>>>(
            Pp, (size_t)1024 * 2048, 8, T1);

        // Stage 3: Y' = T1 @ B2^T  (1024x1024, K=2048, SK=8 -> 512 blocks)
        gemm_bt_sk64<<<dim3(8, 8, 8), 256, 0, stream>>>(
            T1, 2048, B2, 2048, Pp, 1024, (size_t)1024 * 1024, 256);
        reduce_bf<<<dim3(512), 256, 0, stream>>>(
            Pp, (size_t)1024 * 1024, 8, Yp);

        // Stage 4: out = Y' @ Ucat^T + bias (1024x4096, K=1024, SK=4 -> 1024)
        gemm_bt_sk64<<<dim3(32, 8, 4), 256, 0, stream>>>(
            Yp, 1024, Ucat, 1024, Pp, 4096, (size_t)1024 * 4096, 256);
        reduce_f32_bias<<<dim3(2048), 256, 0, stream>>>(
            Pp, (size_t)1024 * 4096, 4, bias, out);
    } else {
        gemm_bt_bf16<false><<<dim3(16, 8), 256, 0, stream>>>(
            x_bf, 4096, B1, 4096, Xp, 2048, nullptr, 4096);
        gemm_bt_bf16<false><<<dim3(16, 8), 256, 0, stream>>>(
            Xp, 2048, Vcat, 2048, T1, 2048, nullptr, 2048);
        gemm_bt_bf16<false><<<dim3(8, 8), 256, 0, stream>>>(
            T1, 2048, B2, 2048, Yp, 1024, nullptr, 2048);
        gemm_bt_bf16<true><<<dim3(32, 8), 256, 0, stream>>>(
            Yp, 1024, Ucat, 1024, out, 4096, bias, 1024);
    }
}